// Round 5
// baseline (15537.141 us; speedup 1.0000x reference)
//
#include <hip/hip_runtime.h>
#include <hip/hip_bf16.h>

typedef unsigned int  u32;
typedef unsigned short u16;
typedef unsigned long long u64;
typedef float f32x16 __attribute__((ext_vector_type(16)));
typedef short bf16x8 __attribute__((ext_vector_type(8)));

#define TT 512
#define BBATCH 32

// ---------- helpers ----------
__device__ __forceinline__ float bfu2f(u16 u){
  union { u32 i; float f; } v; v.i = ((u32)u) << 16; return v.f;
}
__device__ __forceinline__ u16 f2bf_u(float f){
  union { float f; u32 i; } v; v.f = f;
  u32 r = v.i + 0x7fffu + ((v.i >> 16) & 1u);   // RNE
  return (u16)(r >> 16);
}
__device__ __forceinline__ u32 cvtpk_bf(float lo, float hi){
  u32 r; asm("v_cvt_pk_bf16_f32 %0, %1, %2" : "=v"(r) : "v"(lo), "v"(hi)); return r;
}
__device__ __forceinline__ float rcp_fast(float x){
  float r; asm("v_rcp_f32 %0, %1" : "=v"(r) : "v"(x)); return r;
}
__device__ __forceinline__ float sigm(float x){
  return rcp_fast(1.f + __expf(-x));
}
__device__ __forceinline__ float tanh_s(float x){
  float ax = fabsf(x);
  float e = __expf(-2.f * ax);
  float t = (1.f - e) * rcp_fast(1.f + e);
  return copysignf(t, x);
}
// DPP quad_perm cross-lane (VALU pipe, no LDS)
__device__ __forceinline__ float dppq_xor1(float v){
  union { float f; int i; } a, r; a.f = v;
  r.i = __builtin_amdgcn_mov_dpp(a.i, 0xB1, 0xF, 0xF, true);  // (1,0,3,2)
  return r.f;
}
__device__ __forceinline__ float dppq_xor2(float v){
  union { float f; int i; } a, r; a.f = v;
  r.i = __builtin_amdgcn_mov_dpp(a.i, 0x4E, 0xF, 0xF, true);  // (2,3,0,1)
  return r.f;
}

#define SWZ(m) ((u32)(((m) & 15) << 4))

// verified quad transpose (round 4): v2[4g+k] = gate g of cell m=8p+4hi+k
__device__ __forceinline__ void qtrans(const f32x16& acc0, const f32x16& acc1,
                                       int l, float* v2){
  float vals[16], v1[16];
#pragma unroll
  for (int r = 0; r < 16; ++r) vals[r] = acc0[r] + acc1[r];
#pragma unroll
  for (int r = 0; r < 16; ++r){
    float tmp = dppq_xor1(vals[r ^ 4]);
    v1[r] = (((l & 1) ^ ((r >> 2) & 1)) != 0) ? tmp : vals[r];
  }
#pragma unroll
  for (int r = 0; r < 16; ++r){
    float tmp = dppq_xor2(v1[r ^ 8]);
    v2[r] = ((((l >> 1) & 1) ^ ((r >> 3) & 1)) != 0) ? tmp : v1[r];
  }
}

// ---------- fp32 -> bf16 weight convert ----------
__global__ void tobf16(const float* __restrict__ src, u16* __restrict__ dst, int n)
{
  int i = blockIdx.x * blockDim.x + threadIdx.x;
  if (i < n) dst[i] = f2bf_u(src[i]);
}

// ---------- projection GEMM ----------
// abf: 0 = f32 row-major (a_st/a_sb strides), 2 = bf16 transposed [K][16384]
//      (lda in a_st), 3 = f32 transposed [K][16384].
// Output: Cx bf16 [t][s][32b], s=((n&emask)<<2)|(n>>nshift); or Cf f32 rows.
#define BM 128
#define BN 128
#define BK 32

__global__ __launch_bounds__(256) void proj(
    const void* __restrict__ A, int abf, long a_st, long a_sb, int flip, int K,
    const float* __restrict__ W, const float* __restrict__ bias, int N, int nshift,
    u16* __restrict__ Cx, float* __restrict__ Cf, long c_sb, long c_st)
{
  __shared__ float As[BK][BM + 4];
  __shared__ float Bs[BK][BN + 4];
  const int n0 = blockIdx.x * BN;
  const int m0 = blockIdx.y * BM;
  const int tid = threadIdx.x;
  const int tx = tid & 15, ty = tid >> 4;
  const int lr = tid >> 3;          // 0..31
  const int lc = (tid & 7) * 4;     // 0,4,...,28

  float acc[8][8];
#pragma unroll
  for (int i = 0; i < 8; ++i)
#pragma unroll
    for (int j = 0; j < 8; ++j) acc[i][j] = 0.f;

  const float* arow[4];
  if (abf == 0){
#pragma unroll
    for (int rr = 0; rr < 4; ++rr){
      int m = m0 + lr + rr * 32;
      int t = m >> 5, b = m & 31;
      int tq = flip ? (TT - 1 - t) : t;
      arow[rr] = (const float*)A + (size_t)tq * a_st + (size_t)b * a_sb;
    }
  }
  // T-mode thread map
  const int kr = tid >> 3;          // 0..31
  const int mg = tid & 7;

  for (int k0 = 0; k0 < K; k0 += BK){
    if (abf == 0){
#pragma unroll
      for (int rr = 0; rr < 4; ++rr){
        float4 v = *(const float4*)(arow[rr] + k0 + lc);
        int m = lr + rr * 32;
        As[lc + 0][m] = v.x; As[lc + 1][m] = v.y;
        As[lc + 2][m] = v.z; As[lc + 3][m] = v.w;
      }
    } else {
#pragma unroll
      for (int ii = 0; ii < 4; ++ii){
        int ml = mg * 16 + ii * 4;
        int m = m0 + ml;
        int t = m >> 5, b = m & 31;
        int tq = flip ? (TT - 1 - t) : t;
        if (abf == 2){
          ushort4 v = *(const ushort4*)((const u16*)A + (size_t)(k0 + kr) * a_st + tq * 32 + b);
          As[kr][ml + 0] = bfu2f(v.x); As[kr][ml + 1] = bfu2f(v.y);
          As[kr][ml + 2] = bfu2f(v.z); As[kr][ml + 3] = bfu2f(v.w);
        } else {
          float4 v = *(const float4*)((const float*)A + (size_t)(k0 + kr) * a_st + tq * 32 + b);
          As[kr][ml + 0] = v.x; As[kr][ml + 1] = v.y;
          As[kr][ml + 2] = v.z; As[kr][ml + 3] = v.w;
        }
      }
    }
#pragma unroll
    for (int rr = 0; rr < 4; ++rr){
      int n = n0 + lr + rr * 32;
      float4 v = *(const float4*)(W + (size_t)n * K + k0 + lc);
      int nl = lr + rr * 32;
      Bs[lc + 0][nl] = v.x; Bs[lc + 1][nl] = v.y;
      Bs[lc + 2][nl] = v.z; Bs[lc + 3][nl] = v.w;
    }
    __syncthreads();
#pragma unroll
    for (int kk = 0; kk < BK; ++kk){
      float4 a0 = *(const float4*)&As[kk][ty * 8];
      float4 a1 = *(const float4*)&As[kk][ty * 8 + 4];
      float4 b0 = *(const float4*)&Bs[kk][tx * 8];
      float4 b1 = *(const float4*)&Bs[kk][tx * 8 + 4];
      float am[8] = {a0.x,a0.y,a0.z,a0.w,a1.x,a1.y,a1.z,a1.w};
      float bn[8] = {b0.x,b0.y,b0.z,b0.w,b1.x,b1.y,b1.z,b1.w};
#pragma unroll
      for (int i = 0; i < 8; ++i)
#pragma unroll
        for (int j = 0; j < 8; ++j)
          acc[i][j] += am[i] * bn[j];
    }
    __syncthreads();
  }

  float bj[8];
#pragma unroll
  for (int j = 0; j < 8; ++j) bj[j] = bias ? bias[n0 + tx * 8 + j] : 0.f;

  if (Cx){
    // 8 consecutive m = 8 consecutive b of one t
    const int mbase = m0 + ty * 8;
    const int t = mbase >> 5, b0 = mbase & 31;
    const int emask = (1 << nshift) - 1;
#pragma unroll
    for (int j = 0; j < 8; ++j){
      int n = n0 + tx * 8 + j;
      int s = ((n & emask) << 2) | (n >> nshift);
      u16 tmp[8];
#pragma unroll
      for (int i = 0; i < 8; ++i) tmp[i] = f2bf_u(acc[i][j] + bj[j]);
      *(uint4*)(Cx + ((size_t)t * N + s) * 32 + b0) = *(uint4*)tmp;
    }
  } else {
#pragma unroll
    for (int i = 0; i < 8; ++i){
      int m = m0 + ty * 8 + i;
      int t = m >> 5, b = m & 31;
      float* dst = Cf + (size_t)b * c_sb + (size_t)t * c_st + n0 + tx * 8;
      float4 v0 = {acc[i][0] + bj[0], acc[i][1] + bj[1], acc[i][2] + bj[2], acc[i][3] + bj[3]};
      float4 v1 = {acc[i][4] + bj[4], acc[i][5] + bj[5], acc[i][6] + bj[6], acc[i][7] + bj[7]};
      *(float4*)(dst)     = v0;
      *(float4*)(dst + 4) = v1;
    }
  }
}

// ---------- encoder scan: ONE block per direction, 1024 threads ----------
// Wave w (0..15) owns cols nA=w*64+l31, nB=nA+32 (s = e*4+g; W row = g*256+e).
// Whh stationary in VGPRs; xg folded into MFMA via K-augmentation:
//   acc += Id(32x32) x Xg-frag, Xg[n][j] = xc[t][n][j] (b-fastest layout).
// exchT: u16 [512 cols][16384 rows], col = dir*256 + e, row = tq*32 + b.
__global__ __launch_bounds__(1024, 1) void scan_enc4(
    const u16* __restrict__ WF, const u16* __restrict__ WB,
    const u16* __restrict__ xcF, const u16* __restrict__ xcB,
    u16* __restrict__ exchT)
{
  const int dir = blockIdx.x & 7;
  if (dir >= 2) return;
  const u16* __restrict__ Wd = dir ? WB : WF;
  const u16* __restrict__ xc = dir ? xcB : xcF;
  const int tid = threadIdx.x;
  const int l = tid & 63, w = tid >> 6;          // w 0..15
  const int l31 = l & 31, hi = l >> 5, p = l & 3;

  __shared__ u16 hA[2][32 * 256];   // [buf][b][k] swizzled, 32 KB
  { u32* pz = (u32*)hA;
#pragma unroll
    for (int i = 0; i < 8; ++i) pz[tid + i * 1024] = 0;
  }

  const int nA = w * 64 + l31, nB = nA + 32;
  const int growA = (nA & 3) * 256 + (nA >> 2);
  const int growB = (nB & 3) * 256 + (nB >> 2);
  const int kbase = hi << 3;
  bf16x8 bfA[16], bfB[16];
#pragma unroll
  for (int ks = 0; ks < 16; ++ks){
    bfA[ks] = *reinterpret_cast<const bf16x8*>(Wd + (size_t)growA * 256 + ks * 16 + kbase);
    bfB[ks] = *reinterpret_cast<const bf16x8*>(Wd + (size_t)growB * 256 + ks * 16 + kbase);
  }
  // identity A-fragments for the two augmented K-tiles
  bf16x8 id0, id1;
#pragma unroll
  for (int i = 0; i < 8; ++i){
    id0[i] = (short)((l31 == kbase + i)      ? 0x3F80 : 0);
    id1[i] = (short)((l31 == 16 + kbase + i) ? 0x3F80 : 0);
  }

  const int eA = nA >> 2;            // 0..255
  const int eB = eA + 8;
  bf16x8 paA0 = *(const bf16x8*)(xc + (size_t)nA * 32 + kbase);
  bf16x8 paA1 = *(const bf16x8*)(xc + (size_t)nA * 32 + 16 + kbase);
  bf16x8 paB0 = *(const bf16x8*)(xc + (size_t)nB * 32 + kbase);
  bf16x8 paB1 = *(const bf16x8*)(xc + (size_t)nB * 32 + 16 + kbase);

  char* hAb = (char*)hA;
  const int abase = l31 * 512 + (hi << 4);
  const u32 aswz = SWZ(l31);

  float c[8];
#pragma unroll
  for (int i = 0; i < 8; ++i) c[i] = 0.f;

  __syncthreads();

  for (int t = 0; t < TT; ++t){
    f32x16 accA, accB, zc;
#pragma unroll
    for (int i = 0; i < 16; ++i) zc[i] = 0.f;
    accA = __builtin_amdgcn_mfma_f32_32x32x16_bf16(id0, paA0, zc, 0, 0, 0);
    accA = __builtin_amdgcn_mfma_f32_32x32x16_bf16(id1, paA1, accA, 0, 0, 0);
    accB = __builtin_amdgcn_mfma_f32_32x32x16_bf16(id0, paB0, zc, 0, 0, 0);
    accB = __builtin_amdgcn_mfma_f32_32x32x16_bf16(id1, paB1, accB, 0, 0, 0);
    { // prefetch next step's xg fragments (coalesced, latency hidden by MFMA+barrier)
      int tn = (t + 1 < TT) ? t + 1 : t;
      const u16* xn = xc + (size_t)tn * 1024 * 32;
      paA0 = *(const bf16x8*)(xn + (size_t)nA * 32 + kbase);
      paA1 = *(const bf16x8*)(xn + (size_t)nA * 32 + 16 + kbase);
      paB0 = *(const bf16x8*)(xn + (size_t)nB * 32 + kbase);
      paB1 = *(const bf16x8*)(xn + (size_t)nB * 32 + 16 + kbase);
    }
    if (t > 0){
      const char* hb = hAb + (size_t)(t & 1) * 16384;
#pragma unroll
      for (int ks = 0; ks < 16; ++ks){
        bf16x8 a = *(const bf16x8*)(hb + ((u32)(abase + ks * 32) ^ aswz));
        accA = __builtin_amdgcn_mfma_f32_32x32x16_bf16(a, bfA[ks], accA, 0, 0, 0);
        accB = __builtin_amdgcn_mfma_f32_32x32x16_bf16(a, bfB[ks], accB, 0, 0, 0);
      }
    }
    char* hw = hAb + (size_t)((t + 1) & 1) * 16384;
    const int rowb = (dir ? (TT - 1 - t) : t) * 32 + 8 * p + 4 * hi;
    f32x16 zero16;
#pragma unroll
    for (int i = 0; i < 16; ++i) zero16[i] = 0.f;
#pragma unroll
    for (int half = 0; half < 2; ++half){
      float v2[16];
      qtrans(half ? accB : accA, zero16, l, v2);
      const int e = half ? eB : eA;
      float* cc = c + half * 4;
      float h_[4];
#pragma unroll
      for (int k = 0; k < 4; ++k){
        float i_ = sigm(v2[k]);
        float f_ = sigm(v2[4 + k]);
        float g_ = tanh_s(v2[8 + k]);
        float o_ = sigm(v2[12 + k]);
        cc[k] = f_ * cc[k] + i_ * g_;
        h_[k] = o_ * tanh_s(cc[k]);
      }
      u32 lo = cvtpk_bf(h_[0], h_[1]);
      u32 hi2 = cvtpk_bf(h_[2], h_[3]);
      // coalesced u64 store: 4 consecutive rows of col (dir*256+e)
      *(u64*)(exchT + (size_t)(dir * 256 + e) * 16384 + rowb) = ((u64)hi2 << 32) | lo;
      // own hA (next buffer), swizzled [b][k=e]
#pragma unroll
      for (int k = 0; k < 4; ++k){
        int m = 8 * p + 4 * hi + k;
        u16 hv = (k < 2) ? (u16)(lo >> (16 * k)) : (u16)(hi2 >> (16 * (k - 2)));
        *(u16*)(hw + ((u32)(m * 512 + 2 * e) ^ SWZ(m))) = hv;
      }
    }
    __syncthreads();
  }
}

// ---------- decoder scan: single block 512 threads, 1 barrier/step ----------
// Wave w (0..7) owns cols nA=w*64+l31, nB=nA+32 (s=e*4+g; W row=g*128+e).
// yb stored TRANSPOSED f32 [128 cols][16384 rows] for the final proj.
__global__ __launch_bounds__(512, 1) void scan_dec4(
    const u16* __restrict__ Wd, const u16* __restrict__ xc, float* __restrict__ ybT)
{
  const int tid = threadIdx.x;
  const int l = tid & 63, w = tid >> 6;          // w 0..7
  const int l31 = l & 31, hi = l >> 5, p = l & 3;

  __shared__ u16 hA[2][32 * 128];   // 16 KB
  { u32* pz = (u32*)hA;
#pragma unroll
    for (int i = 0; i < 8; ++i) pz[tid + i * 512] = 0;
  }

  const int nA = w * 64 + l31, nB = nA + 32;
  const int growA = (nA & 3) * 128 + (nA >> 2);
  const int growB = (nB & 3) * 128 + (nB >> 2);
  const int kbase = hi << 3;
  bf16x8 bfA[8], bfB[8];
#pragma unroll
  for (int ks = 0; ks < 8; ++ks){
    bfA[ks] = *reinterpret_cast<const bf16x8*>(Wd + (size_t)growA * 128 + ks * 16 + kbase);
    bfB[ks] = *reinterpret_cast<const bf16x8*>(Wd + (size_t)growB * 128 + ks * 16 + kbase);
  }
  bf16x8 id0, id1;
#pragma unroll
  for (int i = 0; i < 8; ++i){
    id0[i] = (short)((l31 == kbase + i)      ? 0x3F80 : 0);
    id1[i] = (short)((l31 == 16 + kbase + i) ? 0x3F80 : 0);
  }

  const int eA = nA >> 2;            // 0..127
  const int eB = eA + 8;
  bf16x8 paA0 = *(const bf16x8*)(xc + (size_t)nA * 32 + kbase);
  bf16x8 paA1 = *(const bf16x8*)(xc + (size_t)nA * 32 + 16 + kbase);
  bf16x8 paB0 = *(const bf16x8*)(xc + (size_t)nB * 32 + kbase);
  bf16x8 paB1 = *(const bf16x8*)(xc + (size_t)nB * 32 + 16 + kbase);

  char* hAb = (char*)hA;
  const int abase = l31 * 256 + (hi << 4);
  const u32 aswz = SWZ(l31);

  float c[8];
#pragma unroll
  for (int i = 0; i < 8; ++i) c[i] = 0.f;

  __syncthreads();

  for (int t = 0; t < TT; ++t){
    f32x16 accA, accB, zc;
#pragma unroll
    for (int i = 0; i < 16; ++i) zc[i] = 0.f;
    accA = __builtin_amdgcn_mfma_f32_32x32x16_bf16(id0, paA0, zc, 0, 0, 0);
    accA = __builtin_amdgcn_mfma_f32_32x32x16_bf16(id1, paA1, accA, 0, 0, 0);
    accB = __builtin_amdgcn_mfma_f32_32x32x16_bf16(id0, paB0, zc, 0, 0, 0);
    accB = __builtin_amdgcn_mfma_f32_32x32x16_bf16(id1, paB1, accB, 0, 0, 0);
    {
      int tn = (t + 1 < TT) ? t + 1 : t;
      const u16* xn = xc + (size_t)tn * 512 * 32;
      paA0 = *(const bf16x8*)(xn + (size_t)nA * 32 + kbase);
      paA1 = *(const bf16x8*)(xn + (size_t)nA * 32 + 16 + kbase);
      paB0 = *(const bf16x8*)(xn + (size_t)nB * 32 + kbase);
      paB1 = *(const bf16x8*)(xn + (size_t)nB * 32 + 16 + kbase);
    }
    if (t > 0){
      const char* hb = hAb + (size_t)(t & 1) * 8192;
#pragma unroll
      for (int ks = 0; ks < 8; ++ks){
        bf16x8 a = *(const bf16x8*)(hb + ((u32)(abase + ks * 32) ^ aswz));
        accA = __builtin_amdgcn_mfma_f32_32x32x16_bf16(a, bfA[ks], accA, 0, 0, 0);
        accB = __builtin_amdgcn_mfma_f32_32x32x16_bf16(a, bfB[ks], accB, 0, 0, 0);
      }
    }
    char* hw = hAb + (size_t)((t + 1) & 1) * 8192;
    const int rowb = t * 32 + 8 * p + 4 * hi;
    f32x16 zero16;
#pragma unroll
    for (int i = 0; i < 16; ++i) zero16[i] = 0.f;
#pragma unroll
    for (int half = 0; half < 2; ++half){
      float v2[16];
      qtrans(half ? accB : accA, zero16, l, v2);
      const int e = half ? eB : eA;
      float* cc = c + half * 4;
      float h_[4];
#pragma unroll
      for (int k = 0; k < 4; ++k){
        float i_ = sigm(v2[k]);
        float f_ = sigm(v2[4 + k]);
        float g_ = tanh_s(v2[8 + k]);
        float o_ = sigm(v2[12 + k]);
        cc[k] = f_ * cc[k] + i_ * g_;
        h_[k] = o_ * tanh_s(cc[k]);
      }
      // coalesced float4: 4 consecutive rows of col e
      float4 yv = {h_[0], h_[1], h_[2], h_[3]};
      *(float4*)(ybT + (size_t)e * 16384 + rowb) = yv;
      u32 lo = cvtpk_bf(h_[0], h_[1]);
      u32 hi2 = cvtpk_bf(h_[2], h_[3]);
#pragma unroll
      for (int k = 0; k < 4; ++k){
        int m = 8 * p + 4 * hi + k;
        u16 hv = (k < 2) ? (u16)(lo >> (16 * k)) : (u16)(hi2 >> (16 * (k - 2)));
        *(u16*)(hw + ((u32)(m * 256 + 2 * e) ^ SWZ(m))) = hv;
      }
    }
    __syncthreads();
  }
}

extern "C" void kernel_launch(void* const* d_in, const int* in_sizes, int n_in,
                              void* d_out, int out_size, void* d_ws, size_t ws_size,
                              hipStream_t stream)
{
  const float* x        = (const float*)d_in[0];
  const float* e0f_Wih  = (const float*)d_in[1];
  const float* e0f_Whh  = (const float*)d_in[2];
  const float* e0f_b    = (const float*)d_in[3];
  const float* e0b_Wih  = (const float*)d_in[4];
  const float* e0b_Whh  = (const float*)d_in[5];
  const float* e0b_b    = (const float*)d_in[6];
  const float* e1f_Wih  = (const float*)d_in[7];
  const float* e1f_Whh  = (const float*)d_in[8];
  const float* e1f_b    = (const float*)d_in[9];
  const float* e1b_Wih  = (const float*)d_in[10];
  const float* e1b_Whh  = (const float*)d_in[11];
  const float* e1b_b    = (const float*)d_in[12];
  const float* dec_Wih  = (const float*)d_in[13];
  const float* dec_Whh  = (const float*)d_in[14];
  const float* dec_b    = (const float*)d_in[15];
  const float* out_W    = (const float*)d_in[16];
  const float* out_b    = (const float*)d_in[17];

  char* p = (char*)d_ws;
  auto alloc = [&](size_t bytes){
    void* r = (void*)p;
    p += (bytes + 255) & ~(size_t)255;
    return r;
  };
  const size_t M = (size_t)TT * BBATCH;                 // 16384
  u16* xcA   = (u16*)alloc((size_t)TT * 1024 * 32 * 2); // 33.6 MB [t][s][b]
  u16* xcB   = (u16*)alloc((size_t)TT * 1024 * 32 * 2); // 33.6 MB
  u16* exchT = (u16*)alloc((size_t)512 * M * 2);        // 16.8 MB [col][row]
  float* ybT = (float*)alloc((size_t)128 * M * 4);      //  8.4 MB [col][row]
  u16* wE0f = (u16*)alloc(1024 * 256 * 2);
  u16* wE0b = (u16*)alloc(1024 * 256 * 2);
  u16* wE1f = (u16*)alloc(1024 * 256 * 2);
  u16* wE1b = (u16*)alloc(1024 * 256 * 2);
  u16* wDec = (u16*)alloc(512 * 128 * 2);

  tobf16<<<1024, 256, 0, stream>>>(e0f_Whh, wE0f, 1024 * 256);
  tobf16<<<1024, 256, 0, stream>>>(e0b_Whh, wE0b, 1024 * 256);
  tobf16<<<1024, 256, 0, stream>>>(e1f_Whh, wE1f, 1024 * 256);
  tobf16<<<1024, 256, 0, stream>>>(e1b_Whh, wE1b, 1024 * 256);
  tobf16<<<256,  256, 0, stream>>>(dec_Whh, wDec, 512 * 128);

  // encoder layer 0 projections: x [B,T,128] f32 -> xc [t][s][b]
  proj<<<dim3(8, 128), 256, 0, stream>>>(x, 0, 128, (long)TT * 128, 0, 128,
      e0f_Wih, e0f_b, 1024, 8, xcA, nullptr, 0, 0);
  proj<<<dim3(8, 128), 256, 0, stream>>>(x, 0, 128, (long)TT * 128, 1, 128,
      e0b_Wih, e0b_b, 1024, 8, xcB, nullptr, 0, 0);
  scan_enc4<<<8, 1024, 0, stream>>>(wE0f, wE0b, xcA, xcB, exchT);

  // encoder layer 1 projections: A = exchT bf16 [512][16384]
  proj<<<dim3(8, 128), 256, 0, stream>>>(exchT, 2, 16384, 0, 0, 512,
      e1f_Wih, e1f_b, 1024, 8, xcA, nullptr, 0, 0);
  proj<<<dim3(8, 128), 256, 0, stream>>>(exchT, 2, 16384, 0, 1, 512,
      e1b_Wih, e1b_b, 1024, 8, xcB, nullptr, 0, 0);
  scan_enc4<<<8, 1024, 0, stream>>>(wE1f, wE1b, xcA, xcB, exchT);

  // decoder projection: A = exchT (layer-1 h) -> xcA [t][s<512][b]
  proj<<<dim3(4, 128), 256, 0, stream>>>(exchT, 2, 16384, 0, 0, 512,
      dec_Wih, dec_b, 512, 7, xcA, nullptr, 0, 0);
  scan_dec4<<<1, 512, 0, stream>>>(wDec, xcA, ybT);

  // output linear: ybT f32 [128][16384] -> d_out [B,T,128] f32
  proj<<<dim3(1, 128), 256, 0, stream>>>(ybT, 3, 16384, 0, 0, 128,
      out_W, out_b, 128, 0, nullptr, (float*)d_out, (long)TT * 128, 128);
}

// Round 6
// 13406.659 us; speedup vs baseline: 1.1589x; 1.1589x over previous
//
#include <hip/hip_runtime.h>
#include <hip/hip_bf16.h>

typedef unsigned int  u32;
typedef unsigned short u16;
typedef unsigned long long u64;
typedef float f32x16 __attribute__((ext_vector_type(16)));
typedef short bf16x8 __attribute__((ext_vector_type(8)));

#define TT 512
#define BBATCH 32

// ---------- helpers ----------
__device__ __forceinline__ float bfu2f(u16 u){
  union { u32 i; float f; } v; v.i = ((u32)u) << 16; return v.f;
}
__device__ __forceinline__ u16 f2bf_u(float f){
  union { float f; u32 i; } v; v.f = f;
  u32 r = v.i + 0x7fffu + ((v.i >> 16) & 1u);   // RNE
  return (u16)(r >> 16);
}
__device__ __forceinline__ float rcp_fast(float x){
  float r; asm("v_rcp_f32 %0, %1" : "=v"(r) : "v"(x)); return r;
}
__device__ __forceinline__ float sigm(float x){
  return rcp_fast(1.f + __expf(-x));
}
__device__ __forceinline__ float tanh_s(float x){
  float ax = fabsf(x);
  float e = __expf(-2.f * ax);
  float t = (1.f - e) * rcp_fast(1.f + e);
  return copysignf(t, x);
}

#define SWZ(m) ((u32)(((m) & 15) << 4))

// ---------- fp32 -> bf16 weight convert ----------
__global__ void tobf16(const float* __restrict__ src, u16* __restrict__ dst, int n)
{
  int i = blockIdx.x * blockDim.x + threadIdx.x;
  if (i < n) dst[i] = f2bf_u(src[i]);
}

__global__ void zflags(u32* flags)
{
  flags[blockIdx.x * 256 + threadIdx.x] = 0;
}

// ---------- projection GEMM ----------
// abf: 0 = f32 row-major, 1 = bf16 row-major, 3 = f32 transposed [K][16384] (lda=a_st)
// Cx (bf16): xc[t][bg][s][8b]  addr = ((t*4+bg)*N + s)*8 + (b&7), s=((n&emask)<<2)|(n>>nshift)
// Cf (f32):  Cf + b*c_sb + t*c_st + n
#define BM 128
#define BN 128
#define BK 32

__global__ __launch_bounds__(256) void proj(
    const void* __restrict__ A, int abf, long a_st, long a_sb, int flip, int K,
    const float* __restrict__ W, const float* __restrict__ bias, int N, int nshift,
    u16* __restrict__ Cx, float* __restrict__ Cf, long c_sb, long c_st)
{
  __shared__ float As[BK][BM + 4];
  __shared__ float Bs[BK][BN + 4];
  const int n0 = blockIdx.x * BN;
  const int m0 = blockIdx.y * BM;
  const int tid = threadIdx.x;
  const int tx = tid & 15, ty = tid >> 4;
  const int lr = tid >> 3;          // 0..31
  const int lc = (tid & 7) * 4;     // 0,4,...,28

  float acc[8][8];
#pragma unroll
  for (int i = 0; i < 8; ++i)
#pragma unroll
    for (int j = 0; j < 8; ++j) acc[i][j] = 0.f;

  const char* arowb[4];
  const int esz = (abf == 1) ? 2 : 4;
  if (abf <= 1){
#pragma unroll
    for (int rr = 0; rr < 4; ++rr){
      int m = m0 + lr + rr * 32;
      int t = m >> 5, b = m & 31;
      int tq = flip ? (TT - 1 - t) : t;
      arowb[rr] = (const char*)A + ((size_t)tq * a_st + (size_t)b * a_sb) * esz;
    }
  }
  const int kr = tid >> 3;          // T-mode: 0..31
  const int mg = tid & 7;

  for (int k0 = 0; k0 < K; k0 += BK){
    if (abf <= 1){
#pragma unroll
      for (int rr = 0; rr < 4; ++rr){
        int m = lr + rr * 32;
        if (abf == 1){
          ushort4 v = *(const ushort4*)((const u16*)arowb[rr] + k0 + lc);
          As[lc + 0][m] = bfu2f(v.x); As[lc + 1][m] = bfu2f(v.y);
          As[lc + 2][m] = bfu2f(v.z); As[lc + 3][m] = bfu2f(v.w);
        } else {
          float4 v = *(const float4*)((const float*)arowb[rr] + k0 + lc);
          As[lc + 0][m] = v.x; As[lc + 1][m] = v.y;
          As[lc + 2][m] = v.z; As[lc + 3][m] = v.w;
        }
      }
    } else {
#pragma unroll
      for (int ii = 0; ii < 4; ++ii){
        int ml = mg * 16 + ii * 4;
        int m = m0 + ml;
        int t = m >> 5, b = m & 31;
        int tq = flip ? (TT - 1 - t) : t;
        float4 v = *(const float4*)((const float*)A + (size_t)(k0 + kr) * a_st + tq * 32 + b);
        As[kr][ml + 0] = v.x; As[kr][ml + 1] = v.y;
        As[kr][ml + 2] = v.z; As[kr][ml + 3] = v.w;
      }
    }
#pragma unroll
    for (int rr = 0; rr < 4; ++rr){
      int n = n0 + lr + rr * 32;
      float4 v = *(const float4*)(W + (size_t)n * K + k0 + lc);
      int nl = lr + rr * 32;
      Bs[lc + 0][nl] = v.x; Bs[lc + 1][nl] = v.y;
      Bs[lc + 2][nl] = v.z; Bs[lc + 3][nl] = v.w;
    }
    __syncthreads();
#pragma unroll
    for (int kk = 0; kk < BK; ++kk){
      float4 a0 = *(const float4*)&As[kk][ty * 8];
      float4 a1 = *(const float4*)&As[kk][ty * 8 + 4];
      float4 b0 = *(const float4*)&Bs[kk][tx * 8];
      float4 b1 = *(const float4*)&Bs[kk][tx * 8 + 4];
      float am[8] = {a0.x,a0.y,a0.z,a0.w,a1.x,a1.y,a1.z,a1.w};
      float bn[8] = {b0.x,b0.y,b0.z,b0.w,b1.x,b1.y,b1.z,b1.w};
#pragma unroll
      for (int i = 0; i < 8; ++i)
#pragma unroll
        for (int j = 0; j < 8; ++j)
          acc[i][j] += am[i] * bn[j];
    }
    __syncthreads();
  }

  float bj[8];
#pragma unroll
  for (int j = 0; j < 8; ++j) bj[j] = bias ? bias[n0 + tx * 8 + j] : 0.f;

  if (Cx){
    const int mbase = m0 + ty * 8;
    const int t = mbase >> 5, b0 = mbase & 31;   // b0 in {0,8,16,24}
    const int bg = b0 >> 3;
    const int emask = (1 << nshift) - 1;
#pragma unroll
    for (int j = 0; j < 8; ++j){
      int n = n0 + tx * 8 + j;
      int s = ((n & emask) << 2) | (n >> nshift);
      u16 tmp[8];
#pragma unroll
      for (int i = 0; i < 8; ++i) tmp[i] = f2bf_u(acc[i][j] + bj[j]);
      *(uint4*)(Cx + (((size_t)t * 4 + bg) * N + s) * 8) = *(uint4*)tmp;
    }
  } else {
#pragma unroll
    for (int i = 0; i < 8; ++i){
      int m = m0 + ty * 8 + i;
      int t = m >> 5, b = m & 31;
      float* dst = Cf + (size_t)b * c_sb + (size_t)t * c_st + n0 + tx * 8;
      float4 v0 = {acc[i][0] + bj[0], acc[i][1] + bj[1], acc[i][2] + bj[2], acc[i][3] + bj[3]};
      float4 v1 = {acc[i][4] + bj[4], acc[i][5] + bj[5], acc[i][6] + bj[6], acc[i][7] + bj[7]};
      *(float4*)(dst)     = v0;
      *(float4*)(dst + 4) = v1;
    }
  }
}

// ---------- encoder scan (operand-swapped MFMA) ----------
// blocks at bx = q*8+dir. Wave w owns s-tile sg = q*256 + w*32 + l31 (s = 4e+g).
// A = W rows (stationary VGPR), B = h (hA[b][k], r3 layout), C row m = s, col n = b.
// acc-init = xg via 2 aug MFMAs: A = xg[s][b-slice] (coalesced from xc[t][bg][s][8b]),
// B = identity. exch u16 [row=tq*32+b][512 col], r3-verbatim flags/staging.
__global__ __launch_bounds__(512, 2) void scan_enc5(
    const u16* __restrict__ WF, const u16* __restrict__ WB,
    const u16* __restrict__ xcF, const u16* __restrict__ xcB,
    u16* __restrict__ exch, u32* __restrict__ flags)
{
  const int bx = blockIdx.x;
  const int dir = bx & 7;
  if (dir >= 2) return;
  const int q = bx >> 3;
  const u16* __restrict__ Wd = dir ? WB : WF;
  const u16* __restrict__ xc = dir ? xcB : xcF;
  const int tid = threadIdx.x;
  const int l = tid & 63, w = tid >> 6;          // 8 waves
  const int l31 = l & 31, hi = l >> 5;

  __shared__ u16 hA[2][32 * 256];   // [buf][b][k] swizzled, 32 KB
  { u32* pz = (u32*)hA;
#pragma unroll
    for (int i = 0; i < 16; ++i) pz[tid + i * 512] = 0;
  }

  // stationary W A-fragments: rows s = sg, torch row = (s&3)*256 + (s>>2)
  const int sg = q * 256 + w * 32 + l31;
  const int wrow = (sg & 3) * 256 + (sg >> 2);
  bf16x8 bfr[16];
#pragma unroll
  for (int ks = 0; ks < 16; ++ks)
    bfr[ks] = *reinterpret_cast<const bf16x8*>(Wd + (size_t)wrow * 256 + ks * 16 + hi * 8);

  // identity B-fragments (aug)
  bf16x8 id0, id1;
#pragma unroll
  for (int i = 0; i < 8; ++i){
    id0[i] = (short)((l31 == hi * 8 + i)      ? 0x3F80 : 0);
    id1[i] = (short)((l31 == 16 + hi * 8 + i) ? 0x3F80 : 0);
  }

  // xg A-fragments (coalesced): bg = hi / 2+hi
  bf16x8 pa0 = *(const bf16x8*)(xc + ((size_t)hi * 1024 + sg) * 8);
  bf16x8 pa1 = *(const bf16x8*)(xc + ((size_t)(2 + hi) * 1024 + sg) * 8);

  char* hAb = (char*)hA;
  const int abase = l31 * 512 + (hi << 4);       // hA[b=l31][k] B-frag base
  const u32 aswz = SWZ(l31);

  const int ebase = q * 64 + w * 8;
  float c[4] = {0.f, 0.f, 0.f, 0.f};

  // exchange-bounce ids
  const int eb_b = tid >> 4, i16 = tid & 15;
  const int flb = dir * 16;

  __syncthreads();

  for (int t = 0; t < TT; ++t){
    f32x16 acc, zc;
#pragma unroll
    for (int i = 0; i < 16; ++i) zc[i] = 0.f;
    acc = __builtin_amdgcn_mfma_f32_32x32x16_bf16(pa0, id0, zc, 0, 0, 0);
    acc = __builtin_amdgcn_mfma_f32_32x32x16_bf16(pa1, id1, acc, 0, 0, 0);
    { // prefetch xg(t+1)
      int tn = (t + 1 < TT) ? t + 1 : t;
      pa0 = *(const bf16x8*)(xc + (((size_t)tn * 4 + hi) * 1024 + sg) * 8);
      pa1 = *(const bf16x8*)(xc + (((size_t)tn * 4 + 2 + hi) * 1024 + sg) * 8);
    }
    if (t > 0){
      const char* hb = hAb + (size_t)(t & 1) * 16384;
#pragma unroll
      for (int ks = 0; ks < 16; ++ks){
        bf16x8 hfr = *(const bf16x8*)(hb + ((u32)(abase + ks * 32) ^ aswz));
        acc = __builtin_amdgcn_mfma_f32_32x32x16_bf16(bfr[ks], hfr, acc, 0, 0, 0);
      }
    }
    // pointwise: lane holds 4 gates of cells (b=l31, e=ebase+2*et+hi) at acc[4*et+g]
    char* hw = hAb + (size_t)((t + 1) & 1) * 16384;
#pragma unroll
    for (int et = 0; et < 4; ++et){
      float i_ = sigm(acc[4 * et + 0]);
      float f_ = sigm(acc[4 * et + 1]);
      float g_ = tanh_s(acc[4 * et + 2]);
      float o_ = sigm(acc[4 * et + 3]);
      c[et] = f_ * c[et] + i_ * g_;
      float h = o_ * tanh_s(c[et]);
      int e = ebase + 2 * et + hi;
      *(u16*)(hw + ((u32)(l31 * 512 + 2 * e) ^ aswz)) = f2bf_u(h);
    }
    __syncthreads();   // B1: own-quarter h complete in hw

    const int rowbase = (dir ? (TT - 1 - t) : t) * 32;
    { // bounce: coalesced u64 exch store of own quarter
      u32 byte = (u32)(eb_b * 512 + (q * 64 + i16 * 4) * 2) ^ SWZ(eb_b);
      u64 hv = *(const u64*)(hw + byte);
      __hip_atomic_store((u64*)exch + (size_t)(rowbase + eb_b) * 128 + dir * 64 + q * 16 + i16,
                         hv, __ATOMIC_RELAXED, __HIP_MEMORY_SCOPE_AGENT);
    }

    if (t == TT - 1) break;

    __syncthreads();   // B2: drains exch stores
    if (tid == 0)
      __hip_atomic_store(&flags[(flb + q) * 32], (u32)(t + 1),
                         __ATOMIC_RELEASE, __HIP_MEMORY_SCOPE_AGENT);
    { // spin on 3 sibling flags
      const int r0 = (q + 1) & 3, r1 = (q + 2) & 3, r2 = (q + 3) & 3;
      const u32 tgt = (u32)(t + 1);
      while (true){
        u32 a0 = __hip_atomic_load(&flags[(flb + r0) * 32], __ATOMIC_ACQUIRE, __HIP_MEMORY_SCOPE_AGENT);
        u32 a1 = __hip_atomic_load(&flags[(flb + r1) * 32], __ATOMIC_ACQUIRE, __HIP_MEMORY_SCOPE_AGENT);
        u32 a2 = __hip_atomic_load(&flags[(flb + r2) * 32], __ATOMIC_ACQUIRE, __HIP_MEMORY_SCOPE_AGENT);
        if (a0 >= tgt && a1 >= tgt && a2 >= tgt) break;
      }
    }
    { // stage 3 remote quarters into hw (r3-verbatim)
      const u64* __restrict__ ex64 = (const u64*)exch;
#pragma unroll
      for (int it = 0; it < 3; ++it){
        int j = tid + it * 512;
        int rqi = j >> 9;
        int rq = rqi + (rqi >= q ? 1 : 0);
        int rem = j & 511;
        int b2 = rem >> 4;
        int u8i = rem & 15;
        u64 v = __hip_atomic_load(ex64 + (size_t)(rowbase + b2) * 128 + dir * 64 + rq * 16 + u8i,
                                  __ATOMIC_RELAXED, __HIP_MEMORY_SCOPE_AGENT);
        *(u64*)(hw + ((u32)(b2 * 512 + rq * 128 + u8i * 8) ^ SWZ(b2))) = v;
      }
    }
    __syncthreads();   // B3
  }
}

// ---------- decoder scan (operand-swapped, single block, 1 barrier/step) ----------
// Wave w owns 2 s-tiles: sA = w*64+l31, sB = sA+32. K=128. ybT f32 [128][16384].
__global__ __launch_bounds__(512, 2) void scan_dec5(
    const u16* __restrict__ Wd, const u16* __restrict__ xc, float* __restrict__ ybT)
{
  const int tid = threadIdx.x;
  const int l = tid & 63, w = tid >> 6;          // 8 waves
  const int l31 = l & 31, hi = l >> 5;

  __shared__ u16 hA[2][32 * 128];   // 16 KB
  { u32* pz = (u32*)hA;
#pragma unroll
    for (int i = 0; i < 8; ++i) pz[tid + i * 512] = 0;
  }

  const int sA = w * 64 + l31, sB = sA + 32;
  const int wrowA = (sA & 3) * 128 + (sA >> 2);
  const int wrowB = (sB & 3) * 128 + (sB >> 2);
  bf16x8 bfA[8], bfB[8];
#pragma unroll
  for (int ks = 0; ks < 8; ++ks){
    bfA[ks] = *reinterpret_cast<const bf16x8*>(Wd + (size_t)wrowA * 128 + ks * 16 + hi * 8);
    bfB[ks] = *reinterpret_cast<const bf16x8*>(Wd + (size_t)wrowB * 128 + ks * 16 + hi * 8);
  }
  bf16x8 id0, id1;
#pragma unroll
  for (int i = 0; i < 8; ++i){
    id0[i] = (short)((l31 == hi * 8 + i)      ? 0x3F80 : 0);
    id1[i] = (short)((l31 == 16 + hi * 8 + i) ? 0x3F80 : 0);
  }

  bf16x8 paA0 = *(const bf16x8*)(xc + ((size_t)hi * 512 + sA) * 8);
  bf16x8 paA1 = *(const bf16x8*)(xc + ((size_t)(2 + hi) * 512 + sA) * 8);
  bf16x8 paB0 = *(const bf16x8*)(xc + ((size_t)hi * 512 + sB) * 8);
  bf16x8 paB1 = *(const bf16x8*)(xc + ((size_t)(2 + hi) * 512 + sB) * 8);

  char* hAb = (char*)hA;
  const int abase = l31 * 256 + (hi << 4);
  const u32 aswz = SWZ(l31);

  const int ebA = w * 16, ebB = w * 16 + 8;
  float c[8];
#pragma unroll
  for (int i = 0; i < 8; ++i) c[i] = 0.f;

  __syncthreads();

  for (int t = 0; t < TT; ++t){
    f32x16 accA, accB, zc;
#pragma unroll
    for (int i = 0; i < 16; ++i) zc[i] = 0.f;
    accA = __builtin_amdgcn_mfma_f32_32x32x16_bf16(paA0, id0, zc, 0, 0, 0);
    accA = __builtin_amdgcn_mfma_f32_32x32x16_bf16(paA1, id1, accA, 0, 0, 0);
    accB = __builtin_amdgcn_mfma_f32_32x32x16_bf16(paB0, id0, zc, 0, 0, 0);
    accB = __builtin_amdgcn_mfma_f32_32x32x16_bf16(paB1, id1, accB, 0, 0, 0);
    {
      int tn = (t + 1 < TT) ? t + 1 : t;
      paA0 = *(const bf16x8*)(xc + (((size_t)tn * 4 + hi) * 512 + sA) * 8);
      paA1 = *(const bf16x8*)(xc + (((size_t)tn * 4 + 2 + hi) * 512 + sA) * 8);
      paB0 = *(const bf16x8*)(xc + (((size_t)tn * 4 + hi) * 512 + sB) * 8);
      paB1 = *(const bf16x8*)(xc + (((size_t)tn * 4 + 2 + hi) * 512 + sB) * 8);
    }
    if (t > 0){
      const char* hb = hAb + (size_t)(t & 1) * 8192;
#pragma unroll
      for (int ks = 0; ks < 8; ++ks){
        bf16x8 hfr = *(const bf16x8*)(hb + ((u32)(abase + ks * 32) ^ aswz));
        accA = __builtin_amdgcn_mfma_f32_32x32x16_bf16(bfA[ks], hfr, accA, 0, 0, 0);
        accB = __builtin_amdgcn_mfma_f32_32x32x16_bf16(bfB[ks], hfr, accB, 0, 0, 0);
      }
    }
    char* hw = hAb + (size_t)((t + 1) & 1) * 8192;
#pragma unroll
    for (int half = 0; half < 2; ++half){
      const int eb = half ? ebB : ebA;
      float* cc = c + half * 4;
#pragma unroll
      for (int et = 0; et < 4; ++et){
        float av[4];
#pragma unroll
        for (int g = 0; g < 4; ++g) av[g] = half ? accB[4 * et + g] : accA[4 * et + g];
        float i_ = sigm(av[0]);
        float f_ = sigm(av[1]);
        float g_ = tanh_s(av[2]);
        float o_ = sigm(av[3]);
        cc[et] = f_ * cc[et] + i_ * g_;
        float h = o_ * tanh_s(cc[et]);
        int e = eb + 2 * et + hi;
        ybT[(size_t)e * 16384 + t * 32 + l31] = h;
        *(u16*)(hw + ((u32)(l31 * 256 + 2 * e) ^ aswz)) = f2bf_u(h);
      }
    }
    __syncthreads();
  }
}

extern "C" void kernel_launch(void* const* d_in, const int* in_sizes, int n_in,
                              void* d_out, int out_size, void* d_ws, size_t ws_size,
                              hipStream_t stream)
{
  const float* x        = (const float*)d_in[0];
  const float* e0f_Wih  = (const float*)d_in[1];
  const float* e0f_Whh  = (const float*)d_in[2];
  const float* e0f_b    = (const float*)d_in[3];
  const float* e0b_Wih  = (const float*)d_in[4];
  const float* e0b_Whh  = (const float*)d_in[5];
  const float* e0b_b    = (const float*)d_in[6];
  const float* e1f_Wih  = (const float*)d_in[7];
  const float* e1f_Whh  = (const float*)d_in[8];
  const float* e1f_b    = (const float*)d_in[9];
  const float* e1b_Wih  = (const float*)d_in[10];
  const float* e1b_Whh  = (const float*)d_in[11];
  const float* e1b_b    = (const float*)d_in[12];
  const float* dec_Wih  = (const float*)d_in[13];
  const float* dec_Whh  = (const float*)d_in[14];
  const float* dec_b    = (const float*)d_in[15];
  const float* out_W    = (const float*)d_in[16];
  const float* out_b    = (const float*)d_in[17];

  char* p = (char*)d_ws;
  auto alloc = [&](size_t bytes){
    void* r = (void*)p;
    p += (bytes + 255) & ~(size_t)255;
    return r;
  };
  const size_t M = (size_t)TT * BBATCH;                 // 16384
  u16* xcA   = (u16*)alloc((size_t)TT * 4 * 1024 * 8 * 2);  // 33.6 MB [t][bg][s][8b]
  u16* xcB   = (u16*)alloc((size_t)TT * 4 * 1024 * 8 * 2);  // 33.6 MB
  u16* exch  = (u16*)alloc(M * 512 * 2);                    // 16.8 MB [row][col]
  float* ybT = (float*)alloc((size_t)128 * M * 4);          //  8.4 MB [col][row]
  u16* wE0f = (u16*)alloc(1024 * 256 * 2);
  u16* wE0b = (u16*)alloc(1024 * 256 * 2);
  u16* wE1f = (u16*)alloc(1024 * 256 * 2);
  u16* wE1b = (u16*)alloc(1024 * 256 * 2);
  u16* wDec = (u16*)alloc(512 * 128 * 2);
  u32* flags = (u32*)alloc(2048 * 4);

  zflags<<<8, 256, 0, stream>>>(flags);
  tobf16<<<1024, 256, 0, stream>>>(e0f_Whh, wE0f, 1024 * 256);
  tobf16<<<1024, 256, 0, stream>>>(e0b_Whh, wE0b, 1024 * 256);
  tobf16<<<1024, 256, 0, stream>>>(e1f_Whh, wE1f, 1024 * 256);
  tobf16<<<1024, 256, 0, stream>>>(e1b_Whh, wE1b, 1024 * 256);
  tobf16<<<256,  256, 0, stream>>>(dec_Whh, wDec, 512 * 128);

  // encoder layer 0 projections: x [B,T,128] f32 -> xc [t][bg][s][8b]
  proj<<<dim3(8, 128), 256, 0, stream>>>(x, 0, 128, (long)TT * 128, 0, 128,
      e0f_Wih, e0f_b, 1024, 8, xcA, nullptr, 0, 0);
  proj<<<dim3(8, 128), 256, 0, stream>>>(x, 0, 128, (long)TT * 128, 1, 128,
      e0b_Wih, e0b_b, 1024, 8, xcB, nullptr, 0, 0);
  scan_enc5<<<32, 512, 0, stream>>>(wE0f, wE0b, xcA, xcB, exch, flags);

  // encoder layer 1 projections: A = exch bf16 [t*32+b][512]
  proj<<<dim3(8, 128), 256, 0, stream>>>(exch, 1, (long)BBATCH * 512, 512, 0, 512,
      e1f_Wih, e1f_b, 1024, 8, xcA, nullptr, 0, 0);
  proj<<<dim3(8, 128), 256, 0, stream>>>(exch, 1, (long)BBATCH * 512, 512, 1, 512,
      e1b_Wih, e1b_b, 1024, 8, xcB, nullptr, 0, 0);
  scan_enc5<<<32, 512, 0, stream>>>(wE1f, wE1b, xcA, xcB, exch, flags + 1024);

  // decoder projection: A = exch bf16 -> xcA [t][bg][s<512][8b]
  proj<<<dim3(4, 128), 256, 0, stream>>>(exch, 1, (long)BBATCH * 512, 512, 0, 512,
      dec_Wih, dec_b, 512, 7, xcA, nullptr, 0, 0);
  scan_dec5<<<1, 512, 0, stream>>>(wDec, xcA, ybT);

  // output linear: ybT f32 [128][16384] -> d_out [B,T,128] f32
  proj<<<dim3(1, 128), 256, 0, stream>>>(ybT, 3, 16384, 0, 0, 128,
      out_W, out_b, 128, 0, nullptr, (float*)d_out, (long)TT * 128, 128);
}

// Round 7
// 6207.669 us; speedup vs baseline: 2.5029x; 2.1597x over previous
//
#include <hip/hip_runtime.h>
#include <hip/hip_bf16.h>

typedef unsigned int  u32;
typedef unsigned short u16;
typedef unsigned long long u64;
typedef float f32x16 __attribute__((ext_vector_type(16)));
typedef short bf16x8 __attribute__((ext_vector_type(8)));

#define TT 512
#define BBATCH 32

// ---------- helpers ----------
__device__ __forceinline__ float bfu2f(u16 u){
  union { u32 i; float f; } v; v.i = ((u32)u) << 16; return v.f;
}
__device__ __forceinline__ u16 f2bf_u(float f){
  union { float f; u32 i; } v; v.f = f;
  u32 r = v.i + 0x7fffu + ((v.i >> 16) & 1u);   // RNE
  return (u16)(r >> 16);
}
__device__ __forceinline__ float rcp_fast(float x){
  float r; asm("v_rcp_f32 %0, %1" : "=v"(r) : "v"(x)); return r;
}
__device__ __forceinline__ float sigm(float x){
  return rcp_fast(1.f + __expf(-x));
}
__device__ __forceinline__ float tanh_s(float x){
  float ax = fabsf(x);
  float e = __expf(-2.f * ax);
  float t = (1.f - e) * rcp_fast(1.f + e);
  return copysignf(t, x);
}

#define SWZ(m) ((u32)(((m) & 15) << 4))

// ---------- fp32 -> bf16 weight convert ----------
__global__ void tobf16(const float* __restrict__ src, u16* __restrict__ dst, int n)
{
  int i = blockIdx.x * blockDim.x + threadIdx.x;
  if (i < n) dst[i] = f2bf_u(src[i]);
}

__global__ void zflags(u32* flags)
{
  flags[blockIdx.x * 256 + threadIdx.x] = 0;
}

// ---------- projection GEMM ----------
// abf: 0 = f32 row-major, 1 = bf16 row-major, 3 = f32 transposed [K][16384] (lda=a_st)
// Cx (bf16): xc[t][bg][s][8b]  addr = ((t*4+bg)*N + s)*8 + (b&7), s=((n&emask)<<2)|(n>>nshift)
// Cf (f32):  Cf + b*c_sb + t*c_st + n
#define BM 128
#define BN 128
#define BK 32

__global__ __launch_bounds__(256) void proj(
    const void* __restrict__ A, int abf, long a_st, long a_sb, int flip, int K,
    const float* __restrict__ W, const float* __restrict__ bias, int N, int nshift,
    u16* __restrict__ Cx, float* __restrict__ Cf, long c_sb, long c_st)
{
  __shared__ float As[BK][BM + 4];
  __shared__ float Bs[BK][BN + 4];
  const int n0 = blockIdx.x * BN;
  const int m0 = blockIdx.y * BM;
  const int tid = threadIdx.x;
  const int tx = tid & 15, ty = tid >> 4;
  const int lr = tid >> 3;          // 0..31
  const int lc = (tid & 7) * 4;     // 0,4,...,28

  float acc[8][8];
#pragma unroll
  for (int i = 0; i < 8; ++i)
#pragma unroll
    for (int j = 0; j < 8; ++j) acc[i][j] = 0.f;

  const char* arowb[4];
  const int esz = (abf == 1) ? 2 : 4;
  if (abf <= 1){
#pragma unroll
    for (int rr = 0; rr < 4; ++rr){
      int m = m0 + lr + rr * 32;
      int t = m >> 5, b = m & 31;
      int tq = flip ? (TT - 1 - t) : t;
      arowb[rr] = (const char*)A + ((size_t)tq * a_st + (size_t)b * a_sb) * esz;
    }
  }
  const int kr = tid >> 3;          // T-mode: 0..31
  const int mg = tid & 7;

  for (int k0 = 0; k0 < K; k0 += BK){
    if (abf <= 1){
#pragma unroll
      for (int rr = 0; rr < 4; ++rr){
        int m = lr + rr * 32;
        if (abf == 1){
          ushort4 v = *(const ushort4*)((const u16*)arowb[rr] + k0 + lc);
          As[lc + 0][m] = bfu2f(v.x); As[lc + 1][m] = bfu2f(v.y);
          As[lc + 2][m] = bfu2f(v.z); As[lc + 3][m] = bfu2f(v.w);
        } else {
          float4 v = *(const float4*)((const float*)arowb[rr] + k0 + lc);
          As[lc + 0][m] = v.x; As[lc + 1][m] = v.y;
          As[lc + 2][m] = v.z; As[lc + 3][m] = v.w;
        }
      }
    } else {
#pragma unroll
      for (int ii = 0; ii < 4; ++ii){
        int ml = mg * 16 + ii * 4;
        int m = m0 + ml;
        int t = m >> 5, b = m & 31;
        int tq = flip ? (TT - 1 - t) : t;
        float4 v = *(const float4*)((const float*)A + (size_t)(k0 + kr) * a_st + tq * 32 + b);
        As[kr][ml + 0] = v.x; As[kr][ml + 1] = v.y;
        As[kr][ml + 2] = v.z; As[kr][ml + 3] = v.w;
      }
    }
#pragma unroll
    for (int rr = 0; rr < 4; ++rr){
      int n = n0 + lr + rr * 32;
      float4 v = *(const float4*)(W + (size_t)n * K + k0 + lc);
      int nl = lr + rr * 32;
      Bs[lc + 0][nl] = v.x; Bs[lc + 1][nl] = v.y;
      Bs[lc + 2][nl] = v.z; Bs[lc + 3][nl] = v.w;
    }
    __syncthreads();
#pragma unroll
    for (int kk = 0; kk < BK; ++kk){
      float4 a0 = *(const float4*)&As[kk][ty * 8];
      float4 a1 = *(const float4*)&As[kk][ty * 8 + 4];
      float4 b0 = *(const float4*)&Bs[kk][tx * 8];
      float4 b1 = *(const float4*)&Bs[kk][tx * 8 + 4];
      float am[8] = {a0.x,a0.y,a0.z,a0.w,a1.x,a1.y,a1.z,a1.w};
      float bn[8] = {b0.x,b0.y,b0.z,b0.w,b1.x,b1.y,b1.z,b1.w};
#pragma unroll
      for (int i = 0; i < 8; ++i)
#pragma unroll
        for (int j = 0; j < 8; ++j)
          acc[i][j] += am[i] * bn[j];
    }
    __syncthreads();
  }

  float bj[8];
#pragma unroll
  for (int j = 0; j < 8; ++j) bj[j] = bias ? bias[n0 + tx * 8 + j] : 0.f;

  if (Cx){
    const int mbase = m0 + ty * 8;
    const int t = mbase >> 5, b0 = mbase & 31;   // b0 in {0,8,16,24}
    const int bg = b0 >> 3;
    const int emask = (1 << nshift) - 1;
#pragma unroll
    for (int j = 0; j < 8; ++j){
      int n = n0 + tx * 8 + j;
      int s = ((n & emask) << 2) | (n >> nshift);
      u16 tmp[8];
#pragma unroll
      for (int i = 0; i < 8; ++i) tmp[i] = f2bf_u(acc[i][j] + bj[j]);
      *(uint4*)(Cx + (((size_t)t * 4 + bg) * N + s) * 8) = *(uint4*)tmp;
    }
  } else {
#pragma unroll
    for (int i = 0; i < 8; ++i){
      int m = m0 + ty * 8 + i;
      int t = m >> 5, b = m & 31;
      float* dst = Cf + (size_t)b * c_sb + (size_t)t * c_st + n0 + tx * 8;
      float4 v0 = {acc[i][0] + bj[0], acc[i][1] + bj[1], acc[i][2] + bj[2], acc[i][3] + bj[3]};
      float4 v1 = {acc[i][4] + bj[4], acc[i][5] + bj[5], acc[i][6] + bj[6], acc[i][7] + bj[7]};
      *(float4*)(dst)     = v0;
      *(float4*)(dst + 4) = v1;
    }
  }
}

// ---------- encoder scan: 2 blocks per direction, operand-swapped MFMA ----------
// Real blocks at bx = half*8 + dir (dir<2, half<2); both halves of a dir share XCD.
// Block owns s in [half*512, half*512+512): wave w tiles sA = half*512+w*64+l31, sB=sA+32.
// A = W rows (stationary VGPR), B = h (hA[b][k]); C row m = s_local, col n = b.
// acc-init = xg via 2 aug MFMAs (A = xg frag from xc[t][bg][s][8b], B = identity).
// exch u16 [row=tq*32+b][512], col = dir*256 + e. Sync: relaxed spin + acquire fence.
__global__ __launch_bounds__(512, 1) void scan_enc6(
    const u16* __restrict__ WF, const u16* __restrict__ WB,
    const u16* __restrict__ xcF, const u16* __restrict__ xcB,
    u16* __restrict__ exch, u32* __restrict__ flags)
{
  const int bx = blockIdx.x;
  const int dir = bx & 7;
  if (dir >= 2) return;
  const int half = bx >> 3;
  const u16* __restrict__ Wd = dir ? WB : WF;
  const u16* __restrict__ xc = dir ? xcB : xcF;
  const int tid = threadIdx.x;
  const int l = tid & 63, w = tid >> 6;          // 8 waves
  const int l31 = l & 31, hi = l >> 5;

  __shared__ u16 hA[2][32 * 256];   // [buf][b][k] swizzled, 32 KB
  { u32* pz = (u32*)hA;
#pragma unroll
    for (int i = 0; i < 16; ++i) pz[tid + i * 512] = 0;
  }

  // stationary W A-fragments for 2 s-tiles
  const int sA = half * 512 + w * 64 + l31;
  const int sB = sA + 32;
  const int wrowA = (sA & 3) * 256 + (sA >> 2);
  const int wrowB = (sB & 3) * 256 + (sB >> 2);
  bf16x8 bfA[16], bfB[16];
#pragma unroll
  for (int ks = 0; ks < 16; ++ks){
    bfA[ks] = *reinterpret_cast<const bf16x8*>(Wd + (size_t)wrowA * 256 + ks * 16 + hi * 8);
    bfB[ks] = *reinterpret_cast<const bf16x8*>(Wd + (size_t)wrowB * 256 + ks * 16 + hi * 8);
  }

  // identity B-fragments (aug)
  bf16x8 id0, id1;
#pragma unroll
  for (int i = 0; i < 8; ++i){
    id0[i] = (short)((l31 == hi * 8 + i)      ? 0x3F80 : 0);
    id1[i] = (short)((l31 == 16 + hi * 8 + i) ? 0x3F80 : 0);
  }

  // xg A-fragments (coalesced)
  bf16x8 paA0 = *(const bf16x8*)(xc + ((size_t)hi * 1024 + sA) * 8);
  bf16x8 paA1 = *(const bf16x8*)(xc + ((size_t)(2 + hi) * 1024 + sA) * 8);
  bf16x8 paB0 = *(const bf16x8*)(xc + ((size_t)hi * 1024 + sB) * 8);
  bf16x8 paB1 = *(const bf16x8*)(xc + ((size_t)(2 + hi) * 1024 + sB) * 8);

  char* hAb = (char*)hA;
  const int abase = l31 * 512 + (hi << 4);       // hA[b=l31][k] B-frag base
  const u32 aswz = SWZ(l31);

  const int ebA = half * 128 + w * 16;
  float c[8];
#pragma unroll
  for (int i = 0; i < 8; ++i) c[i] = 0.f;

  // bounce/stage thread map: 1024 u64 per 32x128 half → 2 per thread
  const int slot_self = dir * 2 + half;
  const int slot_rem  = dir * 2 + (1 - half);

  __syncthreads();

  for (int t = 0; t < TT; ++t){
    f32x16 accA, accB, zc;
#pragma unroll
    for (int i = 0; i < 16; ++i) zc[i] = 0.f;
    accA = __builtin_amdgcn_mfma_f32_32x32x16_bf16(paA0, id0, zc, 0, 0, 0);
    accA = __builtin_amdgcn_mfma_f32_32x32x16_bf16(paA1, id1, accA, 0, 0, 0);
    accB = __builtin_amdgcn_mfma_f32_32x32x16_bf16(paB0, id0, zc, 0, 0, 0);
    accB = __builtin_amdgcn_mfma_f32_32x32x16_bf16(paB1, id1, accB, 0, 0, 0);
    { // prefetch xg(t+1)
      int tn = (t + 1 < TT) ? t + 1 : t;
      paA0 = *(const bf16x8*)(xc + (((size_t)tn * 4 + hi) * 1024 + sA) * 8);
      paA1 = *(const bf16x8*)(xc + (((size_t)tn * 4 + 2 + hi) * 1024 + sA) * 8);
      paB0 = *(const bf16x8*)(xc + (((size_t)tn * 4 + hi) * 1024 + sB) * 8);
      paB1 = *(const bf16x8*)(xc + (((size_t)tn * 4 + 2 + hi) * 1024 + sB) * 8);
    }
    if (t > 0){
      const char* hb = hAb + (size_t)(t & 1) * 16384;
#pragma unroll
      for (int ks = 0; ks < 16; ++ks){
        bf16x8 hfr = *(const bf16x8*)(hb + ((u32)(abase + ks * 32) ^ aswz));
        accA = __builtin_amdgcn_mfma_f32_32x32x16_bf16(bfA[ks], hfr, accA, 0, 0, 0);
        accB = __builtin_amdgcn_mfma_f32_32x32x16_bf16(bfB[ks], hfr, accB, 0, 0, 0);
      }
    }
    // pointwise: lane holds 4 gates of cells (b=l31, e = eb + 2et + hi) at acc[4et+g]
    char* hw = hAb + (size_t)((t + 1) & 1) * 16384;
#pragma unroll
    for (int tile = 0; tile < 2; ++tile){
      const int eb = ebA + (tile ? 8 : 0);
      float* cc = c + tile * 4;
#pragma unroll
      for (int et = 0; et < 4; ++et){
        float av[4];
#pragma unroll
        for (int g = 0; g < 4; ++g) av[g] = tile ? accB[4 * et + g] : accA[4 * et + g];
        float i_ = sigm(av[0]);
        float f_ = sigm(av[1]);
        float g_ = tanh_s(av[2]);
        float o_ = sigm(av[3]);
        cc[et] = f_ * cc[et] + i_ * g_;
        float h = o_ * tanh_s(cc[et]);
        int e = eb + 2 * et + hi;
        *(u16*)(hw + ((u32)(l31 * 512 + 2 * e) ^ aswz)) = f2bf_u(h);
      }
    }
    __syncthreads();   // B1: own-half h complete in hw (LDS)

    const int rowbase = (dir ? (TT - 1 - t) : t) * 32;
    { // bounce: own half (32 rows x 128 cols) -> exch, 2 u64 per thread, coalesced
#pragma unroll
      for (int it = 0; it < 2; ++it){
        int j = tid + it * 512;
        int b2 = j >> 5, i32 = j & 31;
        u32 byte = (u32)(b2 * 512 + half * 256 + i32 * 8) ^ SWZ(b2);
        u64 hv = *(const u64*)(hAb + (size_t)((t + 1) & 1) * 16384 + byte);
        __hip_atomic_store((u64*)exch + (size_t)(rowbase + b2) * 128 + dir * 64 + half * 32 + i32,
                           hv, __ATOMIC_RELAXED, __HIP_MEMORY_SCOPE_AGENT);
      }
    }

    if (t == TT - 1) break;

    __syncthreads();   // B2: all exch stores drained (vmcnt before barrier)
    if (tid == 0)
      __hip_atomic_store(&flags[slot_self * 32], (u32)(t + 1),
                         __ATOMIC_RELEASE, __HIP_MEMORY_SCOPE_AGENT);
    { // relaxed spin (no per-poll L1 invalidate), single acquire fence on exit
      const u32 tgt = (u32)(t + 1);
      while (__hip_atomic_load(&flags[slot_rem * 32],
                               __ATOMIC_RELAXED, __HIP_MEMORY_SCOPE_AGENT) < tgt) {}
      __builtin_amdgcn_fence(__ATOMIC_ACQUIRE, "agent");
    }
    { // stage remote half (32 rows x 128 cols) into hw
#pragma unroll
      for (int it = 0; it < 2; ++it){
        int j = tid + it * 512;
        int b2 = j >> 5, i32 = j & 31;
        u64 v = __hip_atomic_load((const u64*)exch + (size_t)(rowbase + b2) * 128
                                    + dir * 64 + (1 - half) * 32 + i32,
                                  __ATOMIC_RELAXED, __HIP_MEMORY_SCOPE_AGENT);
        u32 byte = (u32)(b2 * 512 + (1 - half) * 256 + i32 * 8) ^ SWZ(b2);
        *(u64*)(hAb + (size_t)((t + 1) & 1) * 16384 + byte) = v;
      }
    }
    __syncthreads();   // B3: hw complete for next step
  }
}

// ---------- decoder scan (operand-swapped, single block, 1 barrier/step) ----------
// Wave w owns 2 s-tiles: sA = w*64+l31, sB = sA+32. K=128. ybT f32 [128][16384].
__global__ __launch_bounds__(512, 2) void scan_dec5(
    const u16* __restrict__ Wd, const u16* __restrict__ xc, float* __restrict__ ybT)
{
  const int tid = threadIdx.x;
  const int l = tid & 63, w = tid >> 6;          // 8 waves
  const int l31 = l & 31, hi = l >> 5;

  __shared__ u16 hA[2][32 * 128];   // 16 KB
  { u32* pz = (u32*)hA;
#pragma unroll
    for (int i = 0; i < 8; ++i) pz[tid + i * 512] = 0;
  }

  const int sA = w * 64 + l31, sB = sA + 32;
  const int wrowA = (sA & 3) * 128 + (sA >> 2);
  const int wrowB = (sB & 3) * 128 + (sB >> 2);
  bf16x8 bfA[8], bfB[8];
#pragma unroll
  for (int ks = 0; ks < 8; ++ks){
    bfA[ks] = *reinterpret_cast<const bf16x8*>(Wd + (size_t)wrowA * 128 + ks * 16 + hi * 8);
    bfB[ks] = *reinterpret_cast<const bf16x8*>(Wd + (size_t)wrowB * 128 + ks * 16 + hi * 8);
  }
  bf16x8 id0, id1;
#pragma unroll
  for (int i = 0; i < 8; ++i){
    id0[i] = (short)((l31 == hi * 8 + i)      ? 0x3F80 : 0);
    id1[i] = (short)((l31 == 16 + hi * 8 + i) ? 0x3F80 : 0);
  }

  bf16x8 paA0 = *(const bf16x8*)(xc + ((size_t)hi * 512 + sA) * 8);
  bf16x8 paA1 = *(const bf16x8*)(xc + ((size_t)(2 + hi) * 512 + sA) * 8);
  bf16x8 paB0 = *(const bf16x8*)(xc + ((size_t)hi * 512 + sB) * 8);
  bf16x8 paB1 = *(const bf16x8*)(xc + ((size_t)(2 + hi) * 512 + sB) * 8);

  char* hAb = (char*)hA;
  const int abase = l31 * 256 + (hi << 4);
  const u32 aswz = SWZ(l31);

  const int ebA = w * 16, ebB = w * 16 + 8;
  float c[8];
#pragma unroll
  for (int i = 0; i < 8; ++i) c[i] = 0.f;

  __syncthreads();

  for (int t = 0; t < TT; ++t){
    f32x16 accA, accB, zc;
#pragma unroll
    for (int i = 0; i < 16; ++i) zc[i] = 0.f;
    accA = __builtin_amdgcn_mfma_f32_32x32x16_bf16(paA0, id0, zc, 0, 0, 0);
    accA = __builtin_amdgcn_mfma_f32_32x32x16_bf16(paA1, id1, accA, 0, 0, 0);
    accB = __builtin_amdgcn_mfma_f32_32x32x16_bf16(paB0, id0, zc, 0, 0, 0);
    accB = __builtin_amdgcn_mfma_f32_32x32x16_bf16(paB1, id1, accB, 0, 0, 0);
    {
      int tn = (t + 1 < TT) ? t + 1 : t;
      paA0 = *(const bf16x8*)(xc + (((size_t)tn * 4 + hi) * 512 + sA) * 8);
      paA1 = *(const bf16x8*)(xc + (((size_t)tn * 4 + 2 + hi) * 512 + sA) * 8);
      paB0 = *(const bf16x8*)(xc + (((size_t)tn * 4 + hi) * 512 + sB) * 8);
      paB1 = *(const bf16x8*)(xc + (((size_t)tn * 4 + 2 + hi) * 512 + sB) * 8);
    }
    if (t > 0){
      const char* hb = hAb + (size_t)(t & 1) * 8192;
#pragma unroll
      for (int ks = 0; ks < 8; ++ks){
        bf16x8 hfr = *(const bf16x8*)(hb + ((u32)(abase + ks * 32) ^ aswz));
        accA = __builtin_amdgcn_mfma_f32_32x32x16_bf16(bfA[ks], hfr, accA, 0, 0, 0);
        accB = __builtin_amdgcn_mfma_f32_32x32x16_bf16(bfB[ks], hfr, accB, 0, 0, 0);
      }
    }
    char* hw = hAb + (size_t)((t + 1) & 1) * 8192;
#pragma unroll
    for (int halfT = 0; halfT < 2; ++halfT){
      const int eb = halfT ? ebB : ebA;
      float* cc = c + halfT * 4;
#pragma unroll
      for (int et = 0; et < 4; ++et){
        float av[4];
#pragma unroll
        for (int g = 0; g < 4; ++g) av[g] = halfT ? accB[4 * et + g] : accA[4 * et + g];
        float i_ = sigm(av[0]);
        float f_ = sigm(av[1]);
        float g_ = tanh_s(av[2]);
        float o_ = sigm(av[3]);
        cc[et] = f_ * cc[et] + i_ * g_;
        float h = o_ * tanh_s(cc[et]);
        int e = eb + 2 * et + hi;
        ybT[(size_t)e * 16384 + t * 32 + l31] = h;
        *(u16*)(hw + ((u32)(l31 * 256 + 2 * e) ^ aswz)) = f2bf_u(h);
      }
    }
    __syncthreads();
  }
}

extern "C" void kernel_launch(void* const* d_in, const int* in_sizes, int n_in,
                              void* d_out, int out_size, void* d_ws, size_t ws_size,
                              hipStream_t stream)
{
  const float* x        = (const float*)d_in[0];
  const float* e0f_Wih  = (const float*)d_in[1];
  const float* e0f_Whh  = (const float*)d_in[2];
  const float* e0f_b    = (const float*)d_in[3];
  const float* e0b_Wih  = (const float*)d_in[4];
  const float* e0b_Whh  = (const float*)d_in[5];
  const float* e0b_b    = (const float*)d_in[6];
  const float* e1f_Wih  = (const float*)d_in[7];
  const float* e1f_Whh  = (const float*)d_in[8];
  const float* e1f_b    = (const float*)d_in[9];
  const float* e1b_Wih  = (const float*)d_in[10];
  const float* e1b_Whh  = (const float*)d_in[11];
  const float* e1b_b    = (const float*)d_in[12];
  const float* dec_Wih  = (const float*)d_in[13];
  const float* dec_Whh  = (const float*)d_in[14];
  const float* dec_b    = (const float*)d_in[15];
  const float* out_W    = (const float*)d_in[16];
  const float* out_b    = (const float*)d_in[17];

  char* p = (char*)d_ws;
  auto alloc = [&](size_t bytes){
    void* r = (void*)p;
    p += (bytes + 255) & ~(size_t)255;
    return r;
  };
  const size_t M = (size_t)TT * BBATCH;                 // 16384
  u16* xcA   = (u16*)alloc((size_t)TT * 4 * 1024 * 8 * 2);  // 33.6 MB [t][bg][s][8b]
  u16* xcB   = (u16*)alloc((size_t)TT * 4 * 1024 * 8 * 2);  // 33.6 MB
  u16* exch  = (u16*)alloc(M * 512 * 2);                    // 16.8 MB [row][col]
  float* ybT = (float*)alloc((size_t)128 * M * 4);          //  8.4 MB [col][row]
  u16* wE0f = (u16*)alloc(1024 * 256 * 2);
  u16* wE0b = (u16*)alloc(1024 * 256 * 2);
  u16* wE1f = (u16*)alloc(1024 * 256 * 2);
  u16* wE1b = (u16*)alloc(1024 * 256 * 2);
  u16* wDec = (u16*)alloc(512 * 128 * 2);
  u32* flags = (u32*)alloc(2048 * 4);

  zflags<<<8, 256, 0, stream>>>(flags);
  tobf16<<<1024, 256, 0, stream>>>(e0f_Whh, wE0f, 1024 * 256);
  tobf16<<<1024, 256, 0, stream>>>(e0b_Whh, wE0b, 1024 * 256);
  tobf16<<<1024, 256, 0, stream>>>(e1f_Whh, wE1f, 1024 * 256);
  tobf16<<<1024, 256, 0, stream>>>(e1b_Whh, wE1b, 1024 * 256);
  tobf16<<<256,  256, 0, stream>>>(dec_Whh, wDec, 512 * 128);

  // encoder layer 0 projections: x [B,T,128] f32 -> xc [t][bg][s][8b]
  proj<<<dim3(8, 128), 256, 0, stream>>>(x, 0, 128, (long)TT * 128, 0, 128,
      e0f_Wih, e0f_b, 1024, 8, xcA, nullptr, 0, 0);
  proj<<<dim3(8, 128), 256, 0, stream>>>(x, 0, 128, (long)TT * 128, 1, 128,
      e0b_Wih, e0b_b, 1024, 8, xcB, nullptr, 0, 0);
  scan_enc6<<<16, 512, 0, stream>>>(wE0f, wE0b, xcA, xcB, exch, flags);

  // encoder layer 1 projections: A = exch bf16 [t*32+b][512]
  proj<<<dim3(8, 128), 256, 0, stream>>>(exch, 1, (long)BBATCH * 512, 512, 0, 512,
      e1f_Wih, e1f_b, 1024, 8, xcA, nullptr, 0, 0);
  proj<<<dim3(8, 128), 256, 0, stream>>>(exch, 1, (long)BBATCH * 512, 512, 1, 512,
      e1b_Wih, e1b_b, 1024, 8, xcB, nullptr, 0, 0);
  scan_enc6<<<16, 512, 0, stream>>>(wE1f, wE1b, xcA, xcB, exch, flags + 1024);

  // decoder projection: A = exch bf16 -> xcA [t][bg][s<512][8b]
  proj<<<dim3(4, 128), 256, 0, stream>>>(exch, 1, (long)BBATCH * 512, 512, 0, 512,
      dec_Wih, dec_b, 512, 7, xcA, nullptr, 0, 0);
  scan_dec5<<<1, 512, 0, stream>>>(wDec, xcA, ybT);

  // output linear: ybT f32 [128][16384] -> d_out [B,T,128] f32
  proj<<<dim3(1, 128), 256, 0, stream>>>(ybT, 3, 16384, 0, 0, 128,
      out_W, out_b, 128, 0, nullptr, (float*)d_out, (long)TT * 128, 128);
}